// Round 1
// baseline (1271.873 us; speedup 1.0000x reference)
//
#include <hip/hip_runtime.h>
#include <math.h>

#define N_ATOMS 50000
#define E_EDGES 100000
#define B_G     50
#define M_M     50
#define NPG     1000
#define DIN     32
#define H1C     32
#define H2C     64
#define DEC     16
#define AAF     95
#define G_DIM   128
#define K_ST    3
#define T_L     6
#define EA_E    98
#define XDIM    159          // H2 + AAF
#define NS      21           // K + T*K weight slices

// ---------------------------------------------------------------------------
// Edge kernel: one lane per edge. msg[o] = sum_f h[f]*(be[f*FOUT+o] +
// sum_d ea[d]*We[d, f*FOUT+o]);  atomicAdd into agg[dst].
// W reads are wave-uniform -> scalar loads (s_load), VALU does pure FMA.
// ---------------------------------------------------------------------------
template<int FIN, int FOUT>
__global__ __launch_bounds__(256) void edge_conv(
    const float* __restrict__ h, const float* __restrict__ ea,
    const int* __restrict__ eidx, const float* __restrict__ We,
    const float* __restrict__ be, float* __restrict__ agg)
{
    int e = blockIdx.x * 256 + threadIdx.x;
    if (e >= E_EDGES) return;
    int s = eidx[e];
    int d = eidx[E_EDGES + e];

    float hv[FIN];
    const float4* hr = (const float4*)(h + (size_t)s * FIN);
    #pragma unroll
    for (int i = 0; i < FIN/4; ++i) {
        float4 v = hr[i];
        hv[4*i]=v.x; hv[4*i+1]=v.y; hv[4*i+2]=v.z; hv[4*i+3]=v.w;
    }
    float av[DEC];
    const float4* er = (const float4*)(ea + (size_t)e * DEC);
    #pragma unroll
    for (int i = 0; i < DEC/4; ++i) {
        float4 v = er[i];
        av[4*i]=v.x; av[4*i+1]=v.y; av[4*i+2]=v.z; av[4*i+3]=v.w;
    }

    float acc[FOUT];
    #pragma unroll
    for (int o = 0; o < FOUT; ++o) acc[o] = 0.f;

    // bias contribution: sum_f h[f]*be[f*FOUT+o]
    for (int f = 0; f < FIN; ++f) {
        float hf = hv[f];
        const float* br = be + f * FOUT;
        #pragma unroll
        for (int o = 0; o < FOUT; ++o) acc[o] += hf * br[o];
    }
    // main term
    for (int dd = 0; dd < DEC; ++dd) {
        float a = av[dd];
        const float* wd = We + (size_t)dd * (FIN * FOUT);
        for (int f = 0; f < FIN; ++f) {
            float u = a * hv[f];
            const float* wr = wd + f * FOUT;
            #pragma unroll
            for (int o = 0; o < FOUT; ++o) acc[o] += u * wr[o];
        }
    }
    float* outp = agg + (size_t)d * FOUT;
    #pragma unroll
    for (int o = 0; o < FOUT; ++o) atomicAdd(outp + o, acc[o]);
}

// ---------------------------------------------------------------------------
// Node update: hout = relu(agg + hin @ root + bias)
// ---------------------------------------------------------------------------
template<int FIN, int FOUT>
__global__ __launch_bounds__(256) void node_update(
    const float* __restrict__ hin, const float* __restrict__ agg,
    const float* __restrict__ root, const float* __restrict__ bias,
    float* __restrict__ hout)
{
    int n = blockIdx.x * 256 + threadIdx.x;
    if (n >= N_ATOMS) return;
    float hv[FIN];
    const float4* hr = (const float4*)(hin + (size_t)n * FIN);
    #pragma unroll
    for (int i = 0; i < FIN/4; ++i) {
        float4 v = hr[i];
        hv[4*i]=v.x; hv[4*i+1]=v.y; hv[4*i+2]=v.z; hv[4*i+3]=v.w;
    }
    float acc[FOUT];
    const float* ar = agg + (size_t)n * FOUT;
    #pragma unroll
    for (int o = 0; o < FOUT; ++o) acc[o] = ar[o] + bias[o];
    for (int f = 0; f < FIN; ++f) {
        float hf = hv[f];
        const float* rr = root + f * FOUT;
        #pragma unroll
        for (int o = 0; o < FOUT; ++o) acc[o] += hf * rr[o];
    }
    float* op = hout + (size_t)n * FOUT;
    #pragma unroll
    for (int o = 0; o < FOUT; ++o) op[o] = fmaxf(acc[o], 0.f);
}

// ---------------------------------------------------------------------------
// Per-graph atom attention readout + monomer segment-sum + concat aa_features
// One block per graph.
// ---------------------------------------------------------------------------
__global__ __launch_bounds__(256) void atom_readout(
    const float* __restrict__ h2, const float* __restrict__ wa,
    const float* __restrict__ ba, const int* __restrict__ labels,
    const float* __restrict__ aaf, float* __restrict__ h_aa)
{
    __shared__ float sc[NPG];
    __shared__ float red[256];
    __shared__ float aa4[4][M_M][H2C];
    int b = blockIdx.x;
    int tid = threadIdx.x;
    const float* hb = h2 + (size_t)b * NPG * H2C;

    for (int n = tid; n < NPG; n += 256) {
        const float* hr = hb + (size_t)n * H2C;
        float sv = ba[0];
        #pragma unroll 8
        for (int o = 0; o < H2C; ++o) sv += hr[o] * wa[o];
        sc[n] = sv;
    }
    __syncthreads();

    float lmax = -1e30f;
    for (int n = tid; n < NPG; n += 256) lmax = fmaxf(lmax, sc[n]);
    red[tid] = lmax;
    __syncthreads();
    for (int off = 128; off > 0; off >>= 1) {
        if (tid < off) red[tid] = fmaxf(red[tid], red[tid + off]);
        __syncthreads();
    }
    float mx = red[0];
    __syncthreads();

    float lsum = 0.f;
    for (int n = tid; n < NPG; n += 256) lsum += expf(sc[n] - mx);
    red[tid] = lsum;
    __syncthreads();
    for (int off = 128; off > 0; off >>= 1) {
        if (tid < off) red[tid] += red[tid + off];
        __syncthreads();
    }
    float invden = 1.f / red[0];

    for (int n = tid; n < NPG; n += 256) sc[n] = expf(sc[n] - mx) * invden;
    for (int i = tid; i < 4 * M_M * H2C; i += 256) ((float*)aa4)[i] = 0.f;
    __syncthreads();

    int q = tid >> 6, o = tid & 63;          // q uniform per wave
    for (int n = q; n < NPG; n += 4) {
        int lbl = labels[b * NPG + n];       // wave-uniform -> s_load
        float w = sc[n];
        float hvv = hb[(size_t)n * H2C + o];
        aa4[q][lbl][o] += hvv * w;           // unique (q,lbl,o) owner
    }
    __syncthreads();

    float* ob = h_aa + (size_t)b * M_M * XDIM;
    const float* ab = aaf + (size_t)b * M_M * AAF;
    for (int i = tid; i < M_M * XDIM; i += 256) {
        int m = i / XDIM, f = i - m * XDIM;
        float v;
        if (f < H2C) v = aa4[0][m][f] + aa4[1][m][f] + aa4[2][m][f] + aa4[3][m][f];
        else         v = ab[m * AAF + (f - H2C)];
        ob[i] = v;
    }
}

// ---------------------------------------------------------------------------
// Amino-graph gcn_norm (tiny, 1 block)
// ---------------------------------------------------------------------------
__global__ void aa_norm_kernel(const int* __restrict__ aei, float* __restrict__ norm)
{
    __shared__ float deg[M_M];
    __shared__ float dinv[M_M];
    int tid = threadIdx.x;
    if (tid < M_M) deg[tid] = 0.f;
    __syncthreads();
    if (tid < EA_E) atomicAdd(&deg[aei[EA_E + tid]], 1.f);
    __syncthreads();
    if (tid < M_M) {
        float dv = deg[tid];
        dinv[tid] = (dv > 0.f) ? (1.f / sqrtf(fmaxf(dv, 1.f))) : 0.f;
    }
    __syncthreads();
    if (tid < EA_E) norm[tid] = dinv[aei[tid]] * dinv[aei[EA_E + tid]];
}

// ---------------------------------------------------------------------------
// Batched root GEMM: RC[b,s,m,o] = x0[b,m,:] @ Wall[s,:,o]
// s<K: arma_init_w[s];  s>=K: arma_root_w[s-K]
// ---------------------------------------------------------------------------
__global__ __launch_bounds__(256) void rc_gemm(
    const float* __restrict__ h_aa, const float* __restrict__ init_w,
    const float* __restrict__ root_w, float* __restrict__ RC)
{
    __shared__ float x0[M_M][160];   // padded rows -> float4-aligned
    int b = blockIdx.x / NS, s = blockIdx.x % NS;
    int tid = threadIdx.x;
    const float* xb = h_aa + (size_t)b * M_M * XDIM;
    for (int i = tid; i < M_M * XDIM; i += 256) {
        int m = i / XDIM, f = i - m * XDIM;
        x0[m][f] = xb[i];
    }
    __syncthreads();
    const float* W = (s < K_ST) ? (init_w + (size_t)s * XDIM * G_DIM)
                                : (root_w + (size_t)(s - K_ST) * XDIM * G_DIM);
    int oo = tid & 127, mh = tid >> 7;
    float acc[25];
    #pragma unroll
    for (int j = 0; j < 25; ++j) acc[j] = 0.f;

    int f = 0;
    for (; f + 4 <= XDIM; f += 4) {
        float w0 = W[(size_t)(f+0) * G_DIM + oo];
        float w1 = W[(size_t)(f+1) * G_DIM + oo];
        float w2 = W[(size_t)(f+2) * G_DIM + oo];
        float w3 = W[(size_t)(f+3) * G_DIM + oo];
        #pragma unroll
        for (int j = 0; j < 25; ++j) {
            int m = 2*j + mh;
            float4 xv = *(const float4*)&x0[m][f];   // uniform -> LDS broadcast
            acc[j] += xv.x*w0 + xv.y*w1 + xv.z*w2 + xv.w*w3;
        }
    }
    for (; f < XDIM; ++f) {
        float w0 = W[(size_t)f * G_DIM + oo];
        #pragma unroll
        for (int j = 0; j < 25; ++j) acc[j] += x0[2*j + mh][f] * w0;
    }
    float* op = RC + ((size_t)(b * NS + s)) * M_M * G_DIM;
    #pragma unroll
    for (int j = 0; j < 25; ++j) op[(2*j + mh) * G_DIM + oo] = acc[j];
}

// ---------------------------------------------------------------------------
// ARMA recurrence: one block per (b,k). LDS ping-pong, T=6 steps.
// ---------------------------------------------------------------------------
__global__ __launch_bounds__(256) void arma_iter(
    const float* __restrict__ RC, const float* __restrict__ arma_w,
    const float* __restrict__ arma_bias, const float* __restrict__ norm,
    const int* __restrict__ aei, float* __restrict__ gfull)
{
    __shared__ float Abuf[M_M * G_DIM];
    __shared__ float Bbuf[M_M * G_DIM];   // "cur"
    int b = blockIdx.x / K_ST, k = blockIdx.x % K_ST;
    int tid = threadIdx.x;
    int oo = tid & 127, mh = tid >> 7;
    const float* rcb = RC + (size_t)b * NS * M_M * G_DIM;

    for (int i = tid; i < M_M * G_DIM; i += 256)
        Bbuf[i] = rcb[(size_t)k * M_M * G_DIM + i];
    __syncthreads();

    for (int t = 0; t < T_L; ++t) {
        if (t > 0) {
            // Abuf = Bbuf @ arma_w[t-1][k]   (contraction index p)
            const float* aw = arma_w + ((size_t)(t-1) * K_ST + k) * G_DIM * G_DIM;
            float acc[25];
            #pragma unroll
            for (int j = 0; j < 25; ++j) acc[j] = 0.f;
            for (int p = 0; p < G_DIM; p += 4) {
                float w0 = aw[(size_t)(p+0) * G_DIM + oo];
                float w1 = aw[(size_t)(p+1) * G_DIM + oo];
                float w2 = aw[(size_t)(p+2) * G_DIM + oo];
                float w3 = aw[(size_t)(p+3) * G_DIM + oo];
                #pragma unroll
                for (int j = 0; j < 25; ++j) {
                    float4 xv = *(const float4*)&Bbuf[(2*j + mh) * G_DIM + p];
                    acc[j] += xv.x*w0 + xv.y*w1 + xv.z*w2 + xv.w*w3;
                }
            }
            __syncthreads();   // everyone done reading Bbuf
            #pragma unroll
            for (int j = 0; j < 25; ++j) Abuf[(2*j + mh) * G_DIM + oo] = acc[j];
            __syncthreads();
        }
        float* src = (t > 0) ? Abuf : Bbuf;
        float* dst = (t > 0) ? Bbuf : Abuf;
        for (int i = tid; i < M_M * G_DIM; i += 256) dst[i] = 0.f;
        __syncthreads();
        if (tid < G_DIM) {   // column-owner propagation, no races
            for (int e = 0; e < EA_E; ++e) {
                int ss = aei[e], dd = aei[EA_E + e];   // uniform -> s_load
                float nv = norm[e];
                dst[dd * G_DIM + tid] += nv * src[ss * G_DIM + tid];
            }
        }
        __syncthreads();
        const float* rct = rcb + (size_t)(K_ST + t * K_ST + k) * M_M * G_DIM;
        const float* bb  = arma_bias + ((size_t)t * K_ST + k) * G_DIM;
        for (int i = tid; i < M_M * G_DIM; i += 256) {
            float v = dst[i] + rct[i] + bb[i & 127];
            Bbuf[i] = (v > 0.f) ? v : 0.f;
        }
        __syncthreads();
    }
    float* gb = gfull + ((size_t)(b * K_ST + k)) * M_M * G_DIM;
    for (int i = tid; i < M_M * G_DIM; i += 256) gb[i] = Bbuf[i];
}

// ---------------------------------------------------------------------------
// Mean over K, amino attention readout, MLP head. One block per graph.
// ---------------------------------------------------------------------------
__global__ __launch_bounds__(128) void aa_readout_mlp(
    const float* __restrict__ gfull, const float* __restrict__ wa,
    const float* __restrict__ ba,
    const float* __restrict__ W1, const float* __restrict__ b1,
    const float* __restrict__ W2, const float* __restrict__ b2,
    const float* __restrict__ W3, const float* __restrict__ b3,
    const float* __restrict__ W4, const float* __restrict__ b4,
    float* __restrict__ out)
{
    __shared__ float g[M_M][G_DIM + 1];   // +1 pad: row reads spread banks
    __shared__ float s2[M_M];
    __shared__ float p[G_DIM];
    __shared__ float r1[64], r2[32], r3[16];
    int b = blockIdx.x, tid = threadIdx.x;
    const float* g0 = gfull + (size_t)b * K_ST * M_M * G_DIM;
    for (int i = tid; i < M_M * G_DIM; i += 128) {
        int m = i >> 7, o = i & 127;
        g[m][o] = (g0[i] + g0[M_M*G_DIM + i] + g0[2*M_M*G_DIM + i]) * (1.f/3.f);
    }
    __syncthreads();
    if (tid < M_M) {
        float sv = ba[0];
        for (int o = 0; o < G_DIM; ++o) sv += g[tid][o] * wa[o];
        s2[tid] = sv;
    }
    __syncthreads();
    if (tid == 0) {
        float mx = -1e30f;
        for (int m = 0; m < M_M; ++m) mx = fmaxf(mx, s2[m]);
        float den = 0.f;
        for (int m = 0; m < M_M; ++m) den += expf(s2[m] - mx);
        float inv = 1.f / den;
        for (int m = 0; m < M_M; ++m) s2[m] = expf(s2[m] - mx) * inv;
    }
    __syncthreads();
    {
        float pv = 0.f;
        for (int m = 0; m < M_M; ++m) pv += g[m][tid] * s2[m];
        p[tid] = pv;
    }
    __syncthreads();
    if (tid < 64) {
        float v = b1[tid];
        for (int i = 0; i < 128; ++i) v += p[i] * W1[i * 64 + tid];
        r1[tid] = fmaxf(v, 0.f);
    }
    __syncthreads();
    if (tid < 32) {
        float v = b2[tid];
        for (int i = 0; i < 64; ++i) v += r1[i] * W2[i * 32 + tid];
        r2[tid] = fmaxf(v, 0.f);
    }
    __syncthreads();
    if (tid < 16) {
        float v = b3[tid];
        for (int i = 0; i < 32; ++i) v += r2[i] * W3[i * 16 + tid];
        r3[tid] = fmaxf(v, 0.f);
    }
    __syncthreads();
    if (tid == 0) {
        float v = b4[0];
        for (int i = 0; i < 16; ++i) v += r3[i] * W4[i];
        out[b] = v;
    }
}

// ---------------------------------------------------------------------------
extern "C" void kernel_launch(void* const* d_in, const int* in_sizes, int n_in,
                              void* d_out, int out_size, void* d_ws, size_t ws_size,
                              hipStream_t stream)
{
    (void)in_sizes; (void)n_in; (void)out_size; (void)ws_size;
    const float* x            = (const float*)d_in[0];
    const float* edge_attr    = (const float*)d_in[1];
    const float* aa_features  = (const float*)d_in[2];
    const int*   edge_index   = (const int*)  d_in[3];
    const int*   mono_labels  = (const int*)  d_in[4];
    const int*   amino_ei     = (const int*)  d_in[5];
    const float* W_e1 = (const float*)d_in[6];
    const float* b_e1 = (const float*)d_in[7];
    const float* root1= (const float*)d_in[8];
    const float* bias1= (const float*)d_in[9];
    const float* W_e2 = (const float*)d_in[10];
    const float* b_e2 = (const float*)d_in[11];
    const float* root2= (const float*)d_in[12];
    const float* bias2= (const float*)d_in[13];
    const float* Wa_atom = (const float*)d_in[14];
    const float* ba_atom = (const float*)d_in[15];
    const float* arma_init_w = (const float*)d_in[16];
    const float* arma_w      = (const float*)d_in[17];
    const float* arma_root_w = (const float*)d_in[18];
    const float* arma_bias   = (const float*)d_in[19];
    const float* Wa_aa = (const float*)d_in[20];
    const float* ba_aa = (const float*)d_in[21];
    const float* W1 = (const float*)d_in[22];
    const float* b1 = (const float*)d_in[23];
    const float* W2 = (const float*)d_in[24];
    const float* b2 = (const float*)d_in[25];
    const float* W3 = (const float*)d_in[26];
    const float* b3 = (const float*)d_in[27];
    const float* W4 = (const float*)d_in[28];
    const float* b4 = (const float*)d_in[29];

    float* ws = (float*)d_ws;
    float* agg1  = ws;                                  // N*32
    float* h1    = agg1 + (size_t)N_ATOMS * H1C;        // N*32
    float* agg2  = h1   + (size_t)N_ATOMS * H1C;        // N*64
    float* h2    = agg2 + (size_t)N_ATOMS * H2C;        // N*64
    float* h_aa  = h2   + (size_t)N_ATOMS * H2C;        // B*M*159
    float* RC    = h_aa + (size_t)B_G * M_M * XDIM;     // B*21*M*128
    float* gfull = RC   + (size_t)B_G * NS * M_M * G_DIM; // B*3*M*128
    float* normv = gfull+ (size_t)B_G * K_ST * M_M * G_DIM; // EA

    hipMemsetAsync(agg1, 0, (size_t)N_ATOMS * H1C * sizeof(float), stream);
    hipMemsetAsync(agg2, 0, (size_t)N_ATOMS * H2C * sizeof(float), stream);

    int eblocks = (E_EDGES + 255) / 256;
    int nblocks = (N_ATOMS + 255) / 256;

    edge_conv<DIN, H1C><<<eblocks, 256, 0, stream>>>(x, edge_attr, edge_index, W_e1, b_e1, agg1);
    node_update<DIN, H1C><<<nblocks, 256, 0, stream>>>(x, agg1, root1, bias1, h1);
    edge_conv<H1C, H2C><<<eblocks, 256, 0, stream>>>(h1, edge_attr, edge_index, W_e2, b_e2, agg2);
    node_update<H1C, H2C><<<nblocks, 256, 0, stream>>>(h1, agg2, root2, bias2, h2);
    atom_readout<<<B_G, 256, 0, stream>>>(h2, Wa_atom, ba_atom, mono_labels, aa_features, h_aa);
    aa_norm_kernel<<<1, 128, 0, stream>>>(amino_ei, normv);
    rc_gemm<<<B_G * NS, 256, 0, stream>>>(h_aa, arma_init_w, arma_root_w, RC);
    arma_iter<<<B_G * K_ST, 256, 0, stream>>>(RC, arma_w, arma_bias, normv, amino_ei, gfull);
    aa_readout_mlp<<<B_G, 128, 0, stream>>>(gfull, Wa_aa, ba_aa, W1, b1, W2, b2, W3, b3, W4, b4,
                                            (float*)d_out);
}

// Round 2
// 1150.333 us; speedup vs baseline: 1.1057x; 1.1057x over previous
//
#include <hip/hip_runtime.h>
#include <math.h>

#define N_ATOMS 50000
#define E_EDGES 100000
#define B_G     50
#define M_M     50
#define NPG     1000
#define DIN     32
#define H1C     32
#define H2C     64
#define DEC     16
#define AAF     95
#define G_DIM   128
#define K_ST    3
#define T_L     6
#define EA_E    98
#define XDIM    159          // H2 + AAF
#define NS      21           // K + T*K weight slices

// ---------------------------------------------------------------------------
// Edge kernel: one lane per (edge, out-chunk). oc is block-uniform so W reads
// stay wave-uniform -> scalar loads; acc[OC<=16] stays in VGPRs (no spill).
// ---------------------------------------------------------------------------
template<int FIN, int FOUT, int OC>
__global__ __launch_bounds__(256) void edge_conv(
    const float* __restrict__ h, const float* __restrict__ ea,
    const int* __restrict__ eidx, const float* __restrict__ We,
    const float* __restrict__ be, float* __restrict__ agg)
{
    constexpr int NCH = FOUT / OC;
    int bb = blockIdx.x / NCH;
    int oc = blockIdx.x % NCH;           // uniform per block
    int obase = oc * OC;
    int e = bb * 256 + threadIdx.x;
    if (e >= E_EDGES) return;
    int s = eidx[e];
    int d = eidx[E_EDGES + e];

    float hv[FIN];
    const float4* hr = (const float4*)(h + (size_t)s * FIN);
    #pragma unroll
    for (int i = 0; i < FIN/4; ++i) {
        float4 v = hr[i];
        hv[4*i]=v.x; hv[4*i+1]=v.y; hv[4*i+2]=v.z; hv[4*i+3]=v.w;
    }
    float av[DEC];
    const float4* er = (const float4*)(ea + (size_t)e * DEC);
    #pragma unroll
    for (int i = 0; i < DEC/4; ++i) {
        float4 v = er[i];
        av[4*i]=v.x; av[4*i+1]=v.y; av[4*i+2]=v.z; av[4*i+3]=v.w;
    }

    float acc[OC];
    #pragma unroll
    for (int o = 0; o < OC; ++o) acc[o] = 0.f;

    // bias contribution: sum_f h[f]*be[f*FOUT+obase+o]
    for (int f = 0; f < FIN; ++f) {
        float hf = hv[f];
        const float* br = be + f * FOUT + obase;
        #pragma unroll
        for (int o = 0; o < OC; ++o) acc[o] += hf * br[o];
    }
    // main term
    for (int dd = 0; dd < DEC; ++dd) {
        float a = av[dd];
        const float* wd = We + (size_t)dd * (FIN * FOUT) + obase;
        for (int f = 0; f < FIN; ++f) {
            float u = a * hv[f];
            const float* wr = wd + f * FOUT;
            #pragma unroll
            for (int o = 0; o < OC; ++o) acc[o] += u * wr[o];
        }
    }
    float* outp = agg + (size_t)d * FOUT + obase;
    #pragma unroll
    for (int o = 0; o < OC; ++o) atomicAdd(outp + o, acc[o]);
}

// ---------------------------------------------------------------------------
// Node update: hout = relu(agg + hin @ root + bias), chunked like edge_conv
// ---------------------------------------------------------------------------
template<int FIN, int FOUT, int OC>
__global__ __launch_bounds__(256) void node_update(
    const float* __restrict__ hin, const float* __restrict__ agg,
    const float* __restrict__ root, const float* __restrict__ bias,
    float* __restrict__ hout)
{
    constexpr int NCH = FOUT / OC;
    int bb = blockIdx.x / NCH;
    int oc = blockIdx.x % NCH;
    int obase = oc * OC;
    int n = bb * 256 + threadIdx.x;
    if (n >= N_ATOMS) return;
    float hv[FIN];
    const float4* hr = (const float4*)(hin + (size_t)n * FIN);
    #pragma unroll
    for (int i = 0; i < FIN/4; ++i) {
        float4 v = hr[i];
        hv[4*i]=v.x; hv[4*i+1]=v.y; hv[4*i+2]=v.z; hv[4*i+3]=v.w;
    }
    float acc[OC];
    const float* ar = agg + (size_t)n * FOUT + obase;
    #pragma unroll
    for (int o = 0; o < OC; ++o) acc[o] = ar[o] + bias[obase + o];
    for (int f = 0; f < FIN; ++f) {
        float hf = hv[f];
        const float* rr = root + f * FOUT + obase;
        #pragma unroll
        for (int o = 0; o < OC; ++o) acc[o] += hf * rr[o];
    }
    float* op = hout + (size_t)n * FOUT + obase;
    #pragma unroll
    for (int o = 0; o < OC; ++o) op[o] = fmaxf(acc[o], 0.f);
}

// ---------------------------------------------------------------------------
// Per-graph atom attention readout + monomer segment-sum + concat aa_features
// One block per graph.
// ---------------------------------------------------------------------------
__global__ __launch_bounds__(256) void atom_readout(
    const float* __restrict__ h2, const float* __restrict__ wa,
    const float* __restrict__ ba, const int* __restrict__ labels,
    const float* __restrict__ aaf, float* __restrict__ h_aa)
{
    __shared__ float sc[NPG];
    __shared__ float red[256];
    __shared__ float aa4[4][M_M][H2C];
    int b = blockIdx.x;
    int tid = threadIdx.x;
    const float* hb = h2 + (size_t)b * NPG * H2C;

    for (int n = tid; n < NPG; n += 256) {
        const float* hr = hb + (size_t)n * H2C;
        float sv = ba[0];
        #pragma unroll 8
        for (int o = 0; o < H2C; ++o) sv += hr[o] * wa[o];
        sc[n] = sv;
    }
    __syncthreads();

    float lmax = -1e30f;
    for (int n = tid; n < NPG; n += 256) lmax = fmaxf(lmax, sc[n]);
    red[tid] = lmax;
    __syncthreads();
    for (int off = 128; off > 0; off >>= 1) {
        if (tid < off) red[tid] = fmaxf(red[tid], red[tid + off]);
        __syncthreads();
    }
    float mx = red[0];
    __syncthreads();

    float lsum = 0.f;
    for (int n = tid; n < NPG; n += 256) lsum += expf(sc[n] - mx);
    red[tid] = lsum;
    __syncthreads();
    for (int off = 128; off > 0; off >>= 1) {
        if (tid < off) red[tid] += red[tid + off];
        __syncthreads();
    }
    float invden = 1.f / red[0];

    for (int n = tid; n < NPG; n += 256) sc[n] = expf(sc[n] - mx) * invden;
    for (int i = tid; i < 4 * M_M * H2C; i += 256) ((float*)aa4)[i] = 0.f;
    __syncthreads();

    int q = tid >> 6, o = tid & 63;          // q uniform per wave
    for (int n = q; n < NPG; n += 4) {
        int lbl = labels[b * NPG + n];       // wave-uniform -> s_load
        float w = sc[n];
        float hvv = hb[(size_t)n * H2C + o];
        aa4[q][lbl][o] += hvv * w;           // unique (q,lbl,o) owner
    }
    __syncthreads();

    float* ob = h_aa + (size_t)b * M_M * XDIM;
    const float* ab = aaf + (size_t)b * M_M * AAF;
    for (int i = tid; i < M_M * XDIM; i += 256) {
        int m = i / XDIM, f = i - m * XDIM;
        float v;
        if (f < H2C) v = aa4[0][m][f] + aa4[1][m][f] + aa4[2][m][f] + aa4[3][m][f];
        else         v = ab[m * AAF + (f - H2C)];
        ob[i] = v;
    }
}

// ---------------------------------------------------------------------------
// Amino-graph gcn_norm (tiny, 1 block)
// ---------------------------------------------------------------------------
__global__ void aa_norm_kernel(const int* __restrict__ aei, float* __restrict__ norm)
{
    __shared__ float deg[M_M];
    __shared__ float dinv[M_M];
    int tid = threadIdx.x;
    if (tid < M_M) deg[tid] = 0.f;
    __syncthreads();
    if (tid < EA_E) atomicAdd(&deg[aei[EA_E + tid]], 1.f);
    __syncthreads();
    if (tid < M_M) {
        float dv = deg[tid];
        dinv[tid] = (dv > 0.f) ? (1.f / sqrtf(fmaxf(dv, 1.f))) : 0.f;
    }
    __syncthreads();
    if (tid < EA_E) norm[tid] = dinv[aei[tid]] * dinv[aei[EA_E + tid]];
}

// ---------------------------------------------------------------------------
// Batched root GEMM: RC[b,s,m,o] = x0[b,m,:] @ Wall[s,:,o]
// s<K: arma_init_w[s];  s>=K: arma_root_w[s-K]
// ---------------------------------------------------------------------------
__global__ __launch_bounds__(256) void rc_gemm(
    const float* __restrict__ h_aa, const float* __restrict__ init_w,
    const float* __restrict__ root_w, float* __restrict__ RC)
{
    __shared__ float x0[M_M][160];   // padded rows -> float4-aligned
    int b = blockIdx.x / NS, s = blockIdx.x % NS;
    int tid = threadIdx.x;
    const float* xb = h_aa + (size_t)b * M_M * XDIM;
    for (int i = tid; i < M_M * XDIM; i += 256) {
        int m = i / XDIM, f = i - m * XDIM;
        x0[m][f] = xb[i];
    }
    __syncthreads();
    const float* W = (s < K_ST) ? (init_w + (size_t)s * XDIM * G_DIM)
                                : (root_w + (size_t)(s - K_ST) * XDIM * G_DIM);
    int oo = tid & 127, mh = tid >> 7;
    float acc[25];
    #pragma unroll
    for (int j = 0; j < 25; ++j) acc[j] = 0.f;

    int f = 0;
    for (; f + 4 <= XDIM; f += 4) {
        float w0 = W[(size_t)(f+0) * G_DIM + oo];
        float w1 = W[(size_t)(f+1) * G_DIM + oo];
        float w2 = W[(size_t)(f+2) * G_DIM + oo];
        float w3 = W[(size_t)(f+3) * G_DIM + oo];
        #pragma unroll
        for (int j = 0; j < 25; ++j) {
            int m = 2*j + mh;
            float4 xv = *(const float4*)&x0[m][f];   // uniform -> LDS broadcast
            acc[j] += xv.x*w0 + xv.y*w1 + xv.z*w2 + xv.w*w3;
        }
    }
    for (; f < XDIM; ++f) {
        float w0 = W[(size_t)f * G_DIM + oo];
        #pragma unroll
        for (int j = 0; j < 25; ++j) acc[j] += x0[2*j + mh][f] * w0;
    }
    float* op = RC + ((size_t)(b * NS + s)) * M_M * G_DIM;
    #pragma unroll
    for (int j = 0; j < 25; ++j) op[(2*j + mh) * G_DIM + oo] = acc[j];
}

// ---------------------------------------------------------------------------
// ARMA recurrence: one block per (b,k). LDS ping-pong, T=6 steps.
// ---------------------------------------------------------------------------
__global__ __launch_bounds__(256) void arma_iter(
    const float* __restrict__ RC, const float* __restrict__ arma_w,
    const float* __restrict__ arma_bias, const float* __restrict__ norm,
    const int* __restrict__ aei, float* __restrict__ gfull)
{
    __shared__ float Abuf[M_M * G_DIM];
    __shared__ float Bbuf[M_M * G_DIM];   // "cur"
    int b = blockIdx.x / K_ST, k = blockIdx.x % K_ST;
    int tid = threadIdx.x;
    int oo = tid & 127, mh = tid >> 7;
    const float* rcb = RC + (size_t)b * NS * M_M * G_DIM;

    for (int i = tid; i < M_M * G_DIM; i += 256)
        Bbuf[i] = rcb[(size_t)k * M_M * G_DIM + i];
    __syncthreads();

    for (int t = 0; t < T_L; ++t) {
        if (t > 0) {
            // Abuf = Bbuf @ arma_w[t-1][k]   (contraction index p)
            const float* aw = arma_w + ((size_t)(t-1) * K_ST + k) * G_DIM * G_DIM;
            float acc[25];
            #pragma unroll
            for (int j = 0; j < 25; ++j) acc[j] = 0.f;
            for (int p = 0; p < G_DIM; p += 4) {
                float w0 = aw[(size_t)(p+0) * G_DIM + oo];
                float w1 = aw[(size_t)(p+1) * G_DIM + oo];
                float w2 = aw[(size_t)(p+2) * G_DIM + oo];
                float w3 = aw[(size_t)(p+3) * G_DIM + oo];
                #pragma unroll
                for (int j = 0; j < 25; ++j) {
                    float4 xv = *(const float4*)&Bbuf[(2*j + mh) * G_DIM + p];
                    acc[j] += xv.x*w0 + xv.y*w1 + xv.z*w2 + xv.w*w3;
                }
            }
            __syncthreads();   // everyone done reading Bbuf
            #pragma unroll
            for (int j = 0; j < 25; ++j) Abuf[(2*j + mh) * G_DIM + oo] = acc[j];
            __syncthreads();
        }
        float* src = (t > 0) ? Abuf : Bbuf;
        float* dst = (t > 0) ? Bbuf : Abuf;
        for (int i = tid; i < M_M * G_DIM; i += 256) dst[i] = 0.f;
        __syncthreads();
        if (tid < G_DIM) {   // column-owner propagation, no races
            for (int e = 0; e < EA_E; ++e) {
                int ss = aei[e], dd = aei[EA_E + e];   // uniform -> s_load
                float nv = norm[e];
                dst[dd * G_DIM + tid] += nv * src[ss * G_DIM + tid];
            }
        }
        __syncthreads();
        const float* rct = rcb + (size_t)(K_ST + t * K_ST + k) * M_M * G_DIM;
        const float* bb  = arma_bias + ((size_t)t * K_ST + k) * G_DIM;
        for (int i = tid; i < M_M * G_DIM; i += 256) {
            float v = dst[i] + rct[i] + bb[i & 127];
            Bbuf[i] = (v > 0.f) ? v : 0.f;
        }
        __syncthreads();
    }
    float* gb = gfull + ((size_t)(b * K_ST + k)) * M_M * G_DIM;
    for (int i = tid; i < M_M * G_DIM; i += 256) gb[i] = Bbuf[i];
}

// ---------------------------------------------------------------------------
// Mean over K, amino attention readout, MLP head. One block per graph.
// ---------------------------------------------------------------------------
__global__ __launch_bounds__(128) void aa_readout_mlp(
    const float* __restrict__ gfull, const float* __restrict__ wa,
    const float* __restrict__ ba,
    const float* __restrict__ W1, const float* __restrict__ b1,
    const float* __restrict__ W2, const float* __restrict__ b2,
    const float* __restrict__ W3, const float* __restrict__ b3,
    const float* __restrict__ W4, const float* __restrict__ b4,
    float* __restrict__ out)
{
    __shared__ float g[M_M][G_DIM + 1];   // +1 pad: row reads spread banks
    __shared__ float s2[M_M];
    __shared__ float p[G_DIM];
    __shared__ float r1[64], r2[32], r3[16];
    int b = blockIdx.x, tid = threadIdx.x;
    const float* g0 = gfull + (size_t)b * K_ST * M_M * G_DIM;
    for (int i = tid; i < M_M * G_DIM; i += 128) {
        int m = i >> 7, o = i & 127;
        g[m][o] = (g0[i] + g0[M_M*G_DIM + i] + g0[2*M_M*G_DIM + i]) * (1.f/3.f);
    }
    __syncthreads();
    if (tid < M_M) {
        float sv = ba[0];
        for (int o = 0; o < G_DIM; ++o) sv += g[tid][o] * wa[o];
        s2[tid] = sv;
    }
    __syncthreads();
    if (tid == 0) {
        float mx = -1e30f;
        for (int m = 0; m < M_M; ++m) mx = fmaxf(mx, s2[m]);
        float den = 0.f;
        for (int m = 0; m < M_M; ++m) den += expf(s2[m] - mx);
        float inv = 1.f / den;
        for (int m = 0; m < M_M; ++m) s2[m] = expf(s2[m] - mx) * inv;
    }
    __syncthreads();
    {
        float pv = 0.f;
        for (int m = 0; m < M_M; ++m) pv += g[m][tid] * s2[m];
        p[tid] = pv;
    }
    __syncthreads();
    if (tid < 64) {
        float v = b1[tid];
        for (int i = 0; i < 128; ++i) v += p[i] * W1[i * 64 + tid];
        r1[tid] = fmaxf(v, 0.f);
    }
    __syncthreads();
    if (tid < 32) {
        float v = b2[tid];
        for (int i = 0; i < 64; ++i) v += r1[i] * W2[i * 32 + tid];
        r2[tid] = fmaxf(v, 0.f);
    }
    __syncthreads();
    if (tid < 16) {
        float v = b3[tid];
        for (int i = 0; i < 32; ++i) v += r2[i] * W3[i * 16 + tid];
        r3[tid] = fmaxf(v, 0.f);
    }
    __syncthreads();
    if (tid == 0) {
        float v = b4[0];
        for (int i = 0; i < 16; ++i) v += r3[i] * W4[i];
        out[b] = v;
    }
}

// ---------------------------------------------------------------------------
extern "C" void kernel_launch(void* const* d_in, const int* in_sizes, int n_in,
                              void* d_out, int out_size, void* d_ws, size_t ws_size,
                              hipStream_t stream)
{
    (void)in_sizes; (void)n_in; (void)out_size; (void)ws_size;
    const float* x            = (const float*)d_in[0];
    const float* edge_attr    = (const float*)d_in[1];
    const float* aa_features  = (const float*)d_in[2];
    const int*   edge_index   = (const int*)  d_in[3];
    const int*   mono_labels  = (const int*)  d_in[4];
    const int*   amino_ei     = (const int*)  d_in[5];
    const float* W_e1 = (const float*)d_in[6];
    const float* b_e1 = (const float*)d_in[7];
    const float* root1= (const float*)d_in[8];
    const float* bias1= (const float*)d_in[9];
    const float* W_e2 = (const float*)d_in[10];
    const float* b_e2 = (const float*)d_in[11];
    const float* root2= (const float*)d_in[12];
    const float* bias2= (const float*)d_in[13];
    const float* Wa_atom = (const float*)d_in[14];
    const float* ba_atom = (const float*)d_in[15];
    const float* arma_init_w = (const float*)d_in[16];
    const float* arma_w      = (const float*)d_in[17];
    const float* arma_root_w = (const float*)d_in[18];
    const float* arma_bias   = (const float*)d_in[19];
    const float* Wa_aa = (const float*)d_in[20];
    const float* ba_aa = (const float*)d_in[21];
    const float* W1 = (const float*)d_in[22];
    const float* b1 = (const float*)d_in[23];
    const float* W2 = (const float*)d_in[24];
    const float* b2 = (const float*)d_in[25];
    const float* W3 = (const float*)d_in[26];
    const float* b3 = (const float*)d_in[27];
    const float* W4 = (const float*)d_in[28];
    const float* b4 = (const float*)d_in[29];

    float* ws = (float*)d_ws;
    float* agg1  = ws;                                  // N*32
    float* h1    = agg1 + (size_t)N_ATOMS * H1C;        // N*32
    float* agg2  = h1   + (size_t)N_ATOMS * H1C;        // N*64
    float* h2    = agg2 + (size_t)N_ATOMS * H2C;        // N*64
    float* h_aa  = h2   + (size_t)N_ATOMS * H2C;        // B*M*159
    float* RC    = h_aa + (size_t)B_G * M_M * XDIM;     // B*21*M*128
    float* gfull = RC   + (size_t)B_G * NS * M_M * G_DIM; // B*3*M*128
    float* normv = gfull+ (size_t)B_G * K_ST * M_M * G_DIM; // EA

    hipMemsetAsync(agg1, 0, (size_t)N_ATOMS * H1C * sizeof(float), stream);
    hipMemsetAsync(agg2, 0, (size_t)N_ATOMS * H2C * sizeof(float), stream);

    int eblocks = (E_EDGES + 255) / 256;
    int nblocks = (N_ATOMS + 255) / 256;

    edge_conv<DIN, H1C, 16><<<eblocks * (H1C/16), 256, 0, stream>>>(
        x, edge_attr, edge_index, W_e1, b_e1, agg1);
    node_update<DIN, H1C, 16><<<nblocks * (H1C/16), 256, 0, stream>>>(
        x, agg1, root1, bias1, h1);
    edge_conv<H1C, H2C, 16><<<eblocks * (H2C/16), 256, 0, stream>>>(
        h1, edge_attr, edge_index, W_e2, b_e2, agg2);
    node_update<H1C, H2C, 16><<<nblocks * (H2C/16), 256, 0, stream>>>(
        h1, agg2, root2, bias2, h2);
    atom_readout<<<B_G, 256, 0, stream>>>(h2, Wa_atom, ba_atom, mono_labels, aa_features, h_aa);
    aa_norm_kernel<<<1, 128, 0, stream>>>(amino_ei, normv);
    rc_gemm<<<B_G * NS, 256, 0, stream>>>(h_aa, arma_init_w, arma_root_w, RC);
    arma_iter<<<B_G * K_ST, 256, 0, stream>>>(RC, arma_w, arma_bias, normv, amino_ei, gfull);
    aa_readout_mlp<<<B_G, 128, 0, stream>>>(gfull, Wa_aa, ba_aa, W1, b1, W2, b2, W3, b3, W4, b4,
                                            (float*)d_out);
}